// Round 5
// baseline (2466.106 us; speedup 1.0000x reference)
//
#include <hip/hip_runtime.h>

// ============================================================================
// GINConvNet: 2 branches x (5 GIN layers + BN) -> pool -> MLP head.
// Round-5 structure:
//  - Activations stored as f16 rows (32 x 2B = 64B = ONE cache line per row;
//    halves random gather line count). All accumulation/BN/head math in f32.
//    (bf16 storage failed at absmax 2.0 in round 1; f16 noise is 8x smaller.)
//  - k_mlp v3: block's contiguous CSR slice staged into LDS (one coalesced
//    sweep, one vmcnt wait) -> neighbor indices come from LDS, so the gather
//    has ONE global-latency level; 8-lane groups issue <=8 row loads
//    back-to-back. Round-4's shfl-broadcast kept 2 dependent miss levels and
//    pinned at 1.3 TB/s; this removes one level.
//  - BN folded into consumers (k_mlp applies prev layer's affine inline;
//    k_pool applies layer-4 affine to pooled sums).
//  - Bucketed CSR build (bucket = dst>>10): L2-resident scatter windows.
//  - Head: pool+fc1xd fused, tiled f32 GEMM 256->1024, split-K atomic GEMM
//    1024->256, final 256->2 reduction.
// Workspace ~105.5 MB.
// ============================================================================

#define N_NODES 500000
#define N_EDGES 2000000
#define N_GRAPH 4096
#define NB      489         // ceil(500000/1024) buckets
#define EPB     3907        // ceil(N_EDGES/512) edges per scatter block
#define ECAP    1536        // LDS capacity for a block's csr slice (mean 1024)

// wsW element offsets (f32 weight table)
#define OFF_W1  0
#define OFF_B1  4805
#define OFF_W2  4960
#define OFF_B2  9765
#define OFF_G   9920
#define OFF_BT  10075
#define OFF_FXW 10230
#define OFF_FXB 18166
#define OFF_F1W 18422
#define OFF_F1B 280566
#define OFF_F2W 281590
#define OFF_F2B 543734
#define OFF_OW  543990
#define OFF_OB  544502
#define TOTW    544504

__device__ __forceinline__ float bf2f(unsigned short u) {
  return __uint_as_float(((unsigned)u) << 16);
}
__device__ __forceinline__ unsigned short f2bf(float f) {
  unsigned b = __float_as_uint(f);
  b += 0x7fffu + ((b >> 16) & 1u);   // RNE
  return (unsigned short)(b >> 16);
}

union H4 { uint2 u; _Float16 h[4]; };
union H32 { uint4 v[4]; _Float16 h[32]; };

// ---------------------------------------------------------------------------
__global__ __launch_bounds__(256) void k_convert(
    const void* a0, const void* a1, const void* a2, const void* a3,
    const void* a4, const void* a5, const void* a6, const void* a7,
    const void* a8, const void* a9, const void* a10, const void* a11,
    const void* a12, const void* a13, float* __restrict__ wsW)
{
  const bool isbf = (*(const unsigned*)a4) == 0x3F803F80u;  // a4 = gammas
  const int i = blockIdx.x * 256 + threadIdx.x;
  if (i >= TOTW) return;
  const void* p; int off;
  if      (i < OFF_B1)  { p = a0;  off = i; }
  else if (i < OFF_W2)  { p = a1;  off = i - OFF_B1; }
  else if (i < OFF_B2)  { p = a2;  off = i - OFF_W2; }
  else if (i < OFF_G)   { p = a3;  off = i - OFF_B2; }
  else if (i < OFF_BT)  { p = a4;  off = i - OFF_G; }
  else if (i < OFF_FXW) { p = a5;  off = i - OFF_BT; }
  else if (i < OFF_FXB) { p = a6;  off = i - OFF_FXW; }
  else if (i < OFF_F1W) { p = a7;  off = i - OFF_FXB; }
  else if (i < OFF_F1B) { p = a8;  off = i - OFF_F1W; }
  else if (i < OFF_F2W) { p = a9;  off = i - OFF_F1B; }
  else if (i < OFF_F2B) { p = a10; off = i - OFF_F2W; }
  else if (i < OFF_OW)  { p = a11; off = i - OFF_F2B; }
  else if (i < OFF_OB)  { p = a12; off = i - OFF_OW; }
  else                  { p = a13; off = i - OFF_OB; }
  wsW[i] = isbf ? bf2f(((const unsigned short*)p)[off]) : ((const float*)p)[off];
}

// ---------------------------------------------------------------------------
// per-branch: pad/copy input x (31 -> 32 feats) to f16 rows; zero stats+cnt
__global__ __launch_bounds__(256) void k_init(
    const void* __restrict__ xin, const void* __restrict__ gam,
    unsigned short* __restrict__ xo, float* __restrict__ stats,
    int* __restrict__ bucketCnt)
{
  const int tid = threadIdx.x;
  const bool isbf = (*(const unsigned*)gam) == 0x3F803F80u;
  const int i = blockIdx.x * 256 + tid;
  if (blockIdx.x == 0) {
    for (int s = tid; s < 320; s += 256) stats[s] = 0.f;
    for (int s = tid; s < 512; s += 256) bucketCnt[s] = 0;
  }
  if (i >= N_NODES) return;
  H32 row;
  if (isbf) {
    const unsigned short* xs = (const unsigned short*)xin;
    #pragma unroll
    for (int f = 0; f < 31; ++f) row.h[f] = (_Float16)bf2f(xs[(size_t)i * 31 + f]);
  } else {
    const float* xs = (const float*)xin;
    #pragma unroll
    for (int f = 0; f < 31; ++f) row.h[f] = (_Float16)xs[(size_t)i * 31 + f];
  }
  row.h[31] = (_Float16)0.f;
  uint4* xw = (uint4*)(xo + (size_t)i * 32);
  #pragma unroll
  for (int q = 0; q < 4; ++q) xw[q] = row.v[q];
}

// ---------------------------------------------------------------------------
// Bucketed CSR build. Pass 1: per-block LDS bucket hist -> global bucketCnt.
__global__ __launch_bounds__(256) void k_bhist(
    const int* __restrict__ ei, int* __restrict__ bucketCnt)
{
  __shared__ int lh[512];
  const int tid = threadIdx.x;
  for (int i = tid; i < 512; i += 256) lh[i] = 0;
  __syncthreads();
  const int e0 = blockIdx.x * EPB;
  const int e1 = min(e0 + EPB, N_EDGES);
  for (int e = e0 + tid; e < e1; e += 256)
    atomicAdd(&lh[ei[N_EDGES + e] >> 10], 1);
  __syncthreads();
  for (int i = tid; i < 512; i += 256)
    if (lh[i]) atomicAdd(&bucketCnt[i], lh[i]);
}

// Pass 2: single-block exclusive scan of 512 bucket counts -> base + cursor.
__global__ __launch_bounds__(512) void k_bscan(
    const int* __restrict__ bucketCnt, int* __restrict__ bucketBase,
    int* __restrict__ cursor)
{
  __shared__ int sh[512];
  const int tid = threadIdx.x;
  const int v = bucketCnt[tid];
  sh[tid] = v;
  __syncthreads();
  for (int off = 1; off < 512; off <<= 1) {
    int t = (tid >= off) ? sh[tid - off] : 0;
    __syncthreads();
    sh[tid] += t;
    __syncthreads();
  }
  const int incl = sh[tid];
  bucketBase[tid + 1] = incl;
  cursor[tid] = incl - v;
  if (tid == 0) bucketBase[0] = 0;
}

// Pass 3: scatter packed (src<<10 | dstLocal) pairs into bucket streams.
__global__ __launch_bounds__(256) void k_bscatter(
    const int* __restrict__ ei, int* __restrict__ cursor,
    unsigned* __restrict__ pairbuf)
{
  __shared__ int lh[512];
  __shared__ int cb[512];
  __shared__ int lcur[512];
  const int tid = threadIdx.x;
  for (int i = tid; i < 512; i += 256) { lh[i] = 0; lcur[i] = 0; }
  __syncthreads();
  const int e0 = blockIdx.x * EPB;
  const int e1 = min(e0 + EPB, N_EDGES);
  for (int e = e0 + tid; e < e1; e += 256)
    atomicAdd(&lh[ei[N_EDGES + e] >> 10], 1);
  __syncthreads();
  for (int i = tid; i < 512; i += 256)
    cb[i] = lh[i] ? atomicAdd(&cursor[i], lh[i]) : 0;
  __syncthreads();
  for (int e = e0 + tid; e < e1; e += 256) {
    const int s = ei[e];
    const int d = ei[N_EDGES + e];
    const int b = d >> 10;
    const int lp = atomicAdd(&lcur[b], 1);
    pairbuf[cb[b] + lp] = ((unsigned)s << 10) | (unsigned)(d & 1023);
  }
}

// Pass 4: one block per bucket — local hist+scan, write rowp + dst-ordered csr.
__global__ __launch_bounds__(256) void k_bbuild(
    const unsigned* __restrict__ pairbuf, const int* __restrict__ bucketBase,
    int* __restrict__ rowp, int* __restrict__ csr)
{
  __shared__ int hist[1024];
  __shared__ int start[1024];
  __shared__ int sh[256];
  const int tid = threadIdx.x;
  const int b = blockIdx.x;
  const int base = bucketBase[b];
  const int cnt  = bucketBase[b + 1] - base;
  const int node0 = b << 10;
  const int nodesHere = min(1024, N_NODES - node0);
  #pragma unroll
  for (int i = tid; i < 1024; i += 256) hist[i] = 0;
  __syncthreads();
  for (int p = tid; p < cnt; p += 256)
    atomicAdd(&hist[pairbuf[base + p] & 1023u], 1);
  __syncthreads();
  const int i4 = tid * 4;
  const int s0 = hist[i4], s1 = hist[i4 + 1], s2 = hist[i4 + 2], s3 = hist[i4 + 3];
  const int tsum = s0 + s1 + s2 + s3;
  sh[tid] = tsum;
  __syncthreads();
  for (int off = 1; off < 256; off <<= 1) {
    int t = (tid >= off) ? sh[tid - off] : 0;
    __syncthreads();
    sh[tid] += t;
    __syncthreads();
  }
  const int ex = sh[tid] - tsum;
  start[i4]     = ex;
  start[i4 + 1] = ex + s0;
  start[i4 + 2] = ex + s0 + s1;
  start[i4 + 3] = ex + s0 + s1 + s2;
  __syncthreads();
  #pragma unroll
  for (int i = tid; i < 1024; i += 256) {
    if (i < nodesHere) rowp[node0 + i] = base + start[i];
    hist[i] = start[i];
  }
  if (b == 0 && tid == 0) rowp[N_NODES] = N_EDGES;
  __syncthreads();
  for (int p = tid; p < cnt; p += 256) {
    const unsigned v = pairbuf[base + p];
    const int dl = (int)(v & 1023u);
    const int pos = atomicAdd(&hist[dl], 1);
    csr[base + pos] = (int)(v >> 10);
  }
}

// ---------------------------------------------------------------------------
// fused [BN-affine of prev layer] + LDS-indexed group gather + MLP + relu +
// BN-stats. xin/xo are f16 rows (32 halves = 64B).
__global__ __launch_bounds__(256) void k_mlp(
    const float* __restrict__ wsW, float* __restrict__ stats,
    const unsigned short* __restrict__ xin, unsigned short* __restrict__ xo,
    const int* __restrict__ rowp, const int* __restrict__ csr, const int l)
{
  __shared__ __align__(16) float W1l[31][32];
  __shared__ __align__(16) float W2l[31][32];
  __shared__ __align__(16) float b1l[32];
  __shared__ __align__(16) float b2l[32];
  __shared__ float as_[32], cs_[32];
  __shared__ float sums[64];
  __shared__ float srow[256 * 33];   // stride 33: <=2-way bank conflicts
  __shared__ int sjb[256];
  __shared__ int sdeg[256];
  __shared__ int ldsIdx[ECAP];
  const int tid = threadIdx.x;
  const int node0 = blockIdx.x * 256;
  const int nodeEnd = min(node0 + 256, N_NODES);

  if (tid < 64) sums[tid] = 0.f;
  for (int idx = tid; idx < 992; idx += 256) {
    const int k = idx >> 5, j = idx & 31;
    float w1 = 0.f, w2 = 0.f;
    if (j < 31) {
      w1 = wsW[OFF_W1 + (l * 31 + k) * 31 + j];
      w2 = wsW[OFF_W2 + (l * 31 + k) * 31 + j];
    }
    W1l[k][j] = w1; W2l[k][j] = w2;
  }
  if (tid < 32) {
    b1l[tid] = (tid < 31) ? wsW[OFF_B1 + l * 31 + tid] : 0.f;
    b2l[tid] = (tid < 31) ? wsW[OFF_B2 + l * 31 + tid] : 0.f;
    if (l == 0) {
      as_[tid] = 1.f; cs_[tid] = 0.f;
    } else {
      const float invN = 1.f / (float)N_NODES;
      const float s = stats[(l - 1) * 64 + tid];
      const float q = stats[(l - 1) * 64 + 32 + tid];
      const float m = s * invN;
      const float v = fmaxf(q * invN - m * m, 0.f);
      const float rstd = rsqrtf(v + 1e-5f);
      const float g  = (tid < 31) ? wsW[OFF_G + (l - 1) * 31 + tid] : 0.f;
      const float be = (tid < 31) ? wsW[OFF_BT + (l - 1) * 31 + tid] : 0.f;
      const float a = g * rstd;
      as_[tid] = a; cs_[tid] = be - m * a;
    }
  }
  // per-node row pointers (coalesced)
  {
    const int n = node0 + tid;
    if (n < N_NODES) {
      const int a = rowp[n];
      sjb[tid] = a; sdeg[tid] = rowp[n + 1] - a;
    } else {
      sjb[tid] = 0; sdeg[tid] = 0;
    }
  }
  // stage the block's contiguous csr slice into LDS (one coalesced sweep)
  const int ebase = rowp[node0];
  const int ecnt  = rowp[nodeEnd] - ebase;
  const bool ovf  = ecnt > ECAP;
  if (!ovf)
    for (int e = tid; e < ecnt; e += 256) ldsIdx[e] = csr[ebase + e];
  __syncthreads();

  // ---- Phase 1: group gather. 8 lanes per node, 8 passes; indices from LDS.
  const int q = tid & 7;
  #pragma unroll
  for (int pass = 0; pass < 8; ++pass) {
    const int nl = pass * 32 + (tid >> 3); // local node 0..255
    const int node = node0 + nl;
    const int jbl = sjb[nl] - ebase;
    const int deg = sdeg[nl];
    float a0 = 0.f, a1 = 0.f, a2 = 0.f, a3 = 0.f;
    if (node < N_NODES) {
      H4 s; s.u = *(const uint2*)(xin + (size_t)node * 32 + 4 * q);
      a0 = (float)s.h[0]; a1 = (float)s.h[1]; a2 = (float)s.h[2]; a3 = (float)s.h[3];
    }
    for (int base = 0; base < deg; base += 8) {
      const int cnt = min(deg - base, 8);
      H4 v[8];
      #pragma unroll
      for (int k = 0; k < 8; ++k) {
        if (k < cnt) {
          const int s = ovf ? csr[ebase + jbl + base + k] : ldsIdx[jbl + base + k];
          v[k].u = *(const uint2*)(xin + (size_t)s * 32 + 4 * q);
        } else {
          v[k].u = make_uint2(0u, 0u);
        }
      }
      #pragma unroll
      for (int k = 0; k < 8; ++k) {
        a0 += (float)v[k].h[0]; a1 += (float)v[k].h[1];
        a2 += (float)v[k].h[2]; a3 += (float)v[k].h[3];
      }
    }
    float* dp = &srow[nl * 33 + 4 * q];
    dp[0] = a0; dp[1] = a1; dp[2] = a2; dp[3] = a3;
  }
  __syncthreads();

  // ---- Phase 2: per-thread MLP on own node from LDS ----
  const int i = node0 + tid;
  const bool valid = i < N_NODES;
  float h[32];
  #pragma unroll
  for (int m = 0; m < 32; ++m) h[m] = srow[tid * 33 + m];
  // fold prev-layer BN: h = a * (y_i + sum y_j) + (1+deg) * c
  const float degp = valid ? (float)(1 + sdeg[tid]) : 0.f;
  #pragma unroll
  for (int m = 0; m < 32; ++m) h[m] = fmaf(h[m], as_[m], degp * cs_[m]);

  float tt[32];
  {
    const float4* b1v = (const float4*)b1l;
    #pragma unroll
    for (int j4 = 0; j4 < 8; ++j4) {
      float4 a = b1v[j4];
      #pragma unroll
      for (int k = 0; k < 31; ++k) {
        const float4 w = *((const float4*)W1l[k] + j4);
        a.x = fmaf(h[k], w.x, a.x);
        a.y = fmaf(h[k], w.y, a.y);
        a.z = fmaf(h[k], w.z, a.z);
        a.w = fmaf(h[k], w.w, a.w);
      }
      tt[4 * j4 + 0] = fmaxf(a.x, 0.f);
      tt[4 * j4 + 1] = fmaxf(a.y, 0.f);
      tt[4 * j4 + 2] = fmaxf(a.z, 0.f);
      tt[4 * j4 + 3] = fmaxf(a.w, 0.f);
    }
  }
  float fs[32];
  {
    const float4* b2v = (const float4*)b2l;
    #pragma unroll
    for (int j4 = 0; j4 < 8; ++j4) {
      float4 a = b2v[j4];
      #pragma unroll
      for (int k = 0; k < 31; ++k) {
        const float4 w = *((const float4*)W2l[k] + j4);
        a.x = fmaf(tt[k], w.x, a.x);
        a.y = fmaf(tt[k], w.y, a.y);
        a.z = fmaf(tt[k], w.z, a.z);
        a.w = fmaf(tt[k], w.w, a.w);
      }
      fs[4 * j4 + 0] = fmaxf(a.x, 0.f);
      fs[4 * j4 + 1] = fmaxf(a.y, 0.f);
      fs[4 * j4 + 2] = fmaxf(a.z, 0.f);
      fs[4 * j4 + 3] = fmaxf(a.w, 0.f);
    }
  }

  if (valid) {
    H32 o;
    #pragma unroll
    for (int m = 0; m < 32; ++m) o.h[m] = (_Float16)fs[m];
    uint4* xw = (uint4*)(xo + (size_t)i * 32);
    #pragma unroll
    for (int qq = 0; qq < 4; ++qq) xw[qq] = o.v[qq];
  } else {
    #pragma unroll
    for (int m = 0; m < 32; ++m) fs[m] = 0.f;
  }

  // BN-stats: fold-exchange reduction over 64 values (sum | sumsq).
  float v64[64];
  #pragma unroll
  for (int m = 0; m < 32; ++m) { v64[m] = fs[m]; v64[32 + m] = fs[m] * fs[m]; }
  const int lane = tid & 63;
  #pragma unroll
  for (int s = 0; s < 6; ++s) {
    const int half = 32 >> s;
    const bool up = (lane >> s) & 1;
    #pragma unroll
    for (int m = 0; m < half; ++m) {
      const float mine = up ? v64[m] : v64[m + half];
      const float rcv = __shfl_xor(mine, 1 << s);
      v64[m] = (up ? v64[m + half] : v64[m]) + rcv;
    }
  }
  const int f = ((lane & 1) << 5) | ((lane & 2) << 3) | ((lane & 4) << 1) |
                ((lane >> 1) & 4) | ((lane >> 3) & 2) | ((lane >> 5) & 1);
  atomicAdd(&sums[f], v64[0]);
  __syncthreads();
  if (tid < 64) atomicAdd(&stats[l * 64 + tid], sums[tid]);
}

// ---------------------------------------------------------------------------
// per-branch: pool pre-BN f16 y over sorted batch, apply layer-4 BN affine,
// then fc1xd + relu -> h [G,256]
__global__ __launch_bounds__(256) void k_pool(
    const float* __restrict__ wsW, const float* __restrict__ stats,
    const unsigned short* __restrict__ xc, const int* __restrict__ batch,
    float* __restrict__ hout, float* __restrict__ hc2f, const int zero_hc)
{
  const int g = blockIdx.x;
  const int tid = threadIdx.x;
  __shared__ float a4[32], c4[32];
  if (tid < 32) {
    const float invN = 1.f / (float)N_NODES;
    const float s = stats[4 * 64 + tid];
    const float q = stats[4 * 64 + 32 + tid];
    const float m = s * invN;
    const float v = fmaxf(q * invN - m * m, 0.f);
    const float rstd = rsqrtf(v + 1e-5f);
    const float gg = (tid < 31) ? wsW[OFF_G + 4 * 31 + tid] : 0.f;
    const float be = (tid < 31) ? wsW[OFF_BT + 4 * 31 + tid] : 0.f;
    const float a = gg * rstd;
    a4[tid] = a; c4[tid] = be - m * a;
  }
  int lo = 0, hi = N_NODES;
  while (lo < hi) { const int mid = (lo + hi) >> 1; if (batch[mid] < g) lo = mid + 1; else hi = mid; }
  const int start = lo;
  int lo2 = lo, hi2 = N_NODES;
  while (lo2 < hi2) { const int mid = (lo2 + hi2) >> 1; if (batch[mid] < g + 1) lo2 = mid + 1; else hi2 = mid; }
  const int end = lo2;

  __shared__ float part[8][33];
  __shared__ float pooled[32];
  const int ff_ = tid & 31, n8 = tid >> 5;
  float p = 0.f;
  const _Float16* xh = (const _Float16*)xc;
  for (int n = start + n8; n < end; n += 8) p += (float)xh[(size_t)n * 32 + ff_];
  part[n8][ff_] = p;
  __syncthreads();
  if (tid < 32) {
    float s = 0.f;
    #pragma unroll
    for (int m = 0; m < 8; ++m) s += part[m][tid];
    pooled[tid] = fmaf(s, a4[tid], (float)(end - start) * c4[tid]);
  }
  __syncthreads();

  float acc = wsW[OFF_FXB + tid];
  for (int ff = 0; ff < 31; ++ff)
    acc = fmaf(pooled[ff], wsW[OFF_FXW + ff * 256 + tid], acc);
  hout[(size_t)g * 256 + tid] = fmaxf(acc, 0.f);
  if (zero_hc) hc2f[(size_t)g * 256 + tid] = 0.f;
}

// ---------------------------------------------------------------------------
// 64x64-tile f32 GEMM. ADD2: A := A + A2 elementwise on load.
// ATOMIC=false: C = relu(acc + bias); ATOMIC=true: atomicAdd into C.
template <bool ADD2, bool ATOMIC>
__global__ __launch_bounds__(256) void k_gemm(
    const float* __restrict__ A, const float* __restrict__ A2,
    const float* __restrict__ B, const float* __restrict__ bias,
    float* __restrict__ C, const int M, const int N, const int K)
{
  __shared__ __align__(16) float AT[64 * 66];
  __shared__ __align__(16) float BT[64 * 66];
  const int tid = threadIdx.x;
  const int row0 = blockIdx.x * 64;
  const int col0 = blockIdx.y * 64;
  const int ktiles = (K / 64) / gridDim.z;
  const int ktbase = blockIdx.z * ktiles;
  float acc[16];
  #pragma unroll
  for (int m = 0; m < 16; ++m) acc[m] = 0.f;
  const int ar = tid >> 2, akq = tid & 3;
  const int bk = tid >> 4, bc = (tid & 15) * 4;
  const int r0 = (tid >> 4) * 4, c0l = (tid & 15) * 4;

  for (int kt = 0; kt < ktiles; ++kt) {
    const int k0 = (ktbase + kt) * 64;
    #pragma unroll
    for (int m = 0; m < 4; ++m) {
      const int k = akq * 16 + m * 4;
      float4 v = *(const float4*)(A + (size_t)(row0 + ar) * K + (k0 + k));
      if constexpr (ADD2) {
        const float4 q = *(const float4*)(A2 + (size_t)(row0 + ar) * K + (k0 + k));
        v.x += q.x; v.y += q.y; v.z += q.z; v.w += q.w;
      }
      AT[(k + 0) * 66 + ar] = v.x; AT[(k + 1) * 66 + ar] = v.y;
      AT[(k + 2) * 66 + ar] = v.z; AT[(k + 3) * 66 + ar] = v.w;
    }
    #pragma unroll
    for (int m = 0; m < 4; ++m) {
      const int k = bk + m * 16;
      const float4 v = *(const float4*)(B + (size_t)(k0 + k) * N + col0 + bc);
      BT[k * 66 + bc + 0] = v.x; BT[k * 66 + bc + 1] = v.y;
      BT[k * 66 + bc + 2] = v.z; BT[k * 66 + bc + 3] = v.w;
    }
    __syncthreads();
    #pragma unroll 8
    for (int k = 0; k < 64; ++k) {
      const float* ap = &AT[k * 66 + r0];
      const float* bp = &BT[k * 66 + c0l];
      const float a0 = ap[0], a1 = ap[1], a2 = ap[2], a3 = ap[3];
      const float b0 = bp[0], b1 = bp[1], b2 = bp[2], b3 = bp[3];
      acc[0]  = fmaf(a0, b0, acc[0]);  acc[1]  = fmaf(a0, b1, acc[1]);
      acc[2]  = fmaf(a0, b2, acc[2]);  acc[3]  = fmaf(a0, b3, acc[3]);
      acc[4]  = fmaf(a1, b0, acc[4]);  acc[5]  = fmaf(a1, b1, acc[5]);
      acc[6]  = fmaf(a1, b2, acc[6]);  acc[7]  = fmaf(a1, b3, acc[7]);
      acc[8]  = fmaf(a2, b0, acc[8]);  acc[9]  = fmaf(a2, b1, acc[9]);
      acc[10] = fmaf(a2, b2, acc[10]); acc[11] = fmaf(a2, b3, acc[11]);
      acc[12] = fmaf(a3, b0, acc[12]); acc[13] = fmaf(a3, b1, acc[13]);
      acc[14] = fmaf(a3, b2, acc[14]); acc[15] = fmaf(a3, b3, acc[15]);
    }
    __syncthreads();
  }

  if constexpr (ATOMIC) {
    #pragma unroll
    for (int ii = 0; ii < 4; ++ii)
      #pragma unroll
      for (int jj = 0; jj < 4; ++jj)
        atomicAdd(&C[(size_t)(row0 + r0 + ii) * N + col0 + c0l + jj], acc[4 * ii + jj]);
  } else {
    #pragma unroll
    for (int ii = 0; ii < 4; ++ii) {
      float4 st;
      st.x = fmaxf(acc[4 * ii + 0] + bias[col0 + c0l + 0], 0.f);
      st.y = fmaxf(acc[4 * ii + 1] + bias[col0 + c0l + 1], 0.f);
      st.z = fmaxf(acc[4 * ii + 2] + bias[col0 + c0l + 2], 0.f);
      st.w = fmaxf(acc[4 * ii + 3] + bias[col0 + c0l + 3], 0.f);
      *(float4*)(C + (size_t)(row0 + r0 + ii) * N + col0 + c0l) = st;
    }
  }
}

// ---------------------------------------------------------------------------
// relu(hc2f + fc2_b) @ out_W + out_b  -> d_out (bf16 or f32 per sniff)
__global__ __launch_bounds__(256) void k_out(
    const float* __restrict__ wsW, const float* __restrict__ hc2f,
    void* __restrict__ dout, const void* __restrict__ gam)
{
  const int tid = threadIdx.x;
  const int g = blockIdx.x * 4 + (tid >> 6);
  const int lane = tid & 63;
  float p0 = 0.f, p1 = 0.f;
  #pragma unroll
  for (int m = 0; m < 4; ++m) {
    const int k = lane + m * 64;
    const float v = fmaxf(hc2f[(size_t)g * 256 + k] + wsW[OFF_F2B + k], 0.f);
    p0 = fmaf(v, wsW[OFF_OW + 2 * k], p0);
    p1 = fmaf(v, wsW[OFF_OW + 2 * k + 1], p1);
  }
  #pragma unroll
  for (int st = 0; st < 6; ++st) {
    const int msk = 1 << st;
    p0 += __shfl_xor(p0, msk);
    p1 += __shfl_xor(p1, msk);
  }
  if (lane == 0) {
    const float o0 = p0 + wsW[OFF_OB];
    const float o1 = p1 + wsW[OFF_OB + 1];
    const bool isbf = (*(const unsigned*)gam) == 0x3F803F80u;
    if (isbf) {
      unsigned short* o = (unsigned short*)dout;
      o[2 * g] = f2bf(o0); o[2 * g + 1] = f2bf(o1);
    } else {
      float* o = (float*)dout;
      o[2 * g] = o0; o[2 * g + 1] = o1;
    }
  }
}

// ===========================================================================
extern "C" void kernel_launch(void* const* d_in, const int* in_sizes, int n_in,
                              void* d_out, int out_size, void* d_ws, size_t ws_size,
                              hipStream_t stream)
{
  (void)in_sizes; (void)n_in; (void)out_size; (void)ws_size;
  char* ws = (char*)d_ws;
  unsigned short* act0 = (unsigned short*)(ws + 0ull);          // 32,000,000
  unsigned short* act1 = (unsigned short*)(ws + 32000000ull);   // 32,000,000
  int* csr         = (int*)(ws + 64000000ull);      //  8,000,000
  int* rowp        = (int*)(ws + 72000000ull);      //  2,000,016
  int* bucketBase  = (int*)(ws + 74000016ull);      //      2,064
  int* cursor      = (int*)(ws + 74002080ull);      //      2,048
  int* bucketCnt   = (int*)(ws + 74004128ull);      //      2,048
  float* stats     = (float*)(ws + 74006176ull);    //      1,280
  float* wsW       = (float*)(ws + 74007456ull);    //  2,178,016
  float* ha        = (float*)(ws + 76185472ull);    //  4,194,304
  float* hb        = (float*)(ws + 80379776ull);    //  4,194,304
  float* xcb       = (float*)(ws + 84574080ull);    // 16,777,216 (aliases pairbuf)
  float* hc2f      = (float*)(ws + 101351296ull);   //  4,194,304
  unsigned* pairbuf = (unsigned*)xcb;               //  8,000,000 (pre-GEMM only)
  // total ~105.5 MB

  const void* gam = d_in[10];

  k_convert<<<dim3(2127), 256, 0, stream>>>(
      d_in[6], d_in[7], d_in[8], d_in[9], d_in[10], d_in[11], d_in[12],
      d_in[13], d_in[14], d_in[15], d_in[16], d_in[17], d_in[18], d_in[19], wsW);

  for (int br = 0; br < 2; ++br) {
    const void* x_in = br ? d_in[3] : d_in[0];
    const int* ei    = (const int*)(br ? d_in[4] : d_in[1]);
    const int* batch = (const int*)(br ? d_in[5] : d_in[2]);
    float* hout      = br ? hb : ha;

    k_init<<<dim3(1954), 256, 0, stream>>>(x_in, gam, act0, stats, bucketCnt);
    k_bhist<<<dim3(512), 256, 0, stream>>>(ei, bucketCnt);
    k_bscan<<<dim3(1), 512, 0, stream>>>(bucketCnt, bucketBase, cursor);
    k_bscatter<<<dim3(512), 256, 0, stream>>>(ei, cursor, pairbuf);
    k_bbuild<<<dim3(NB), 256, 0, stream>>>(pairbuf, bucketBase, rowp, csr);

    unsigned short* bufs[2] = {act0, act1};
    for (int l = 0; l < 5; ++l) {
      unsigned short* xin = bufs[l & 1];
      unsigned short* xo  = bufs[(l + 1) & 1];
      k_mlp<<<dim3(1954), 256, 0, stream>>>(wsW, stats, xin, xo, rowp, csr, l);
    }
    // after 5 layers, pre-BN activations live in act1 (layer-4 BN in pool)
    k_pool<<<dim3(4096), 256, 0, stream>>>(wsW, stats, act1, batch, hout, hc2f, br == 0 ? 1 : 0);
  }

  k_gemm<true, false><<<dim3(64, 16, 1), 256, 0, stream>>>(
      ha, hb, wsW + OFF_F1W, wsW + OFF_F1B, xcb, 4096, 1024, 256);
  k_gemm<false, true><<<dim3(64, 4, 4), 256, 0, stream>>>(
      xcb, (const float*)nullptr, wsW + OFF_F2W, (const float*)nullptr,
      hc2f, 4096, 256, 1024);
  k_out<<<dim3(1024), 256, 0, stream>>>(wsW, hc2f, d_out, gam);
}

// Round 6
// 1481.874 us; speedup vs baseline: 1.6642x; 1.6642x over previous
//
#include <hip/hip_runtime.h>

// ============================================================================
// GINConvNet: 2 branches x (5 GIN layers + BN) -> pool -> MLP head.
// Round-6 structure:
//  - f16 activation rows (64B = 1 line). All math f32.
//  - k_mlp v4: 4-lane groups (16B dwordx4 per lane), 4 passes/wave (half the
//    round-trips of round 5); CSR slice staged to LDS; srow handoff in f16
//    (stride 40 halves) -> LDS ~37KB -> 4 blocks/CU; launch_bounds(256,4).
//  - BN stats atomics REPLICATED over 64 banks (blockIdx&63) to kill
//    same-line RMW serialization; consumers bank-sum in prologue.
//  - BN folded into consumers; bucketed CSR build; f32 GEMM head.
// Workspace ~105.6 MB.
// ============================================================================

#define N_NODES 500000
#define N_EDGES 2000000
#define N_GRAPH 4096
#define NB      489         // ceil(500000/1024) buckets
#define EPB     3907        // ceil(N_EDGES/512) edges per scatter block
#define ECAP    1280        // LDS capacity for a block's csr slice (mean 1024, sigma 32)

// wsW element offsets (f32 weight table)
#define OFF_W1  0
#define OFF_B1  4805
#define OFF_W2  4960
#define OFF_B2  9765
#define OFF_G   9920
#define OFF_BT  10075
#define OFF_FXW 10230
#define OFF_FXB 18166
#define OFF_F1W 18422
#define OFF_F1B 280566
#define OFF_F2W 281590
#define OFF_F2B 543734
#define OFF_OW  543990
#define OFF_OB  544502
#define TOTW    544504

__device__ __forceinline__ float bf2f(unsigned short u) {
  return __uint_as_float(((unsigned)u) << 16);
}
__device__ __forceinline__ unsigned short f2bf(float f) {
  unsigned b = __float_as_uint(f);
  b += 0x7fffu + ((b >> 16) & 1u);   // RNE
  return (unsigned short)(b >> 16);
}

union H8 { uint4 v; _Float16 h[8]; };
union H32 { uint4 v[4]; _Float16 h[32]; };

// ---------------------------------------------------------------------------
__global__ __launch_bounds__(256) void k_convert(
    const void* a0, const void* a1, const void* a2, const void* a3,
    const void* a4, const void* a5, const void* a6, const void* a7,
    const void* a8, const void* a9, const void* a10, const void* a11,
    const void* a12, const void* a13, float* __restrict__ wsW)
{
  const bool isbf = (*(const unsigned*)a4) == 0x3F803F80u;  // a4 = gammas
  const int i = blockIdx.x * 256 + threadIdx.x;
  if (i >= TOTW) return;
  const void* p; int off;
  if      (i < OFF_B1)  { p = a0;  off = i; }
  else if (i < OFF_W2)  { p = a1;  off = i - OFF_B1; }
  else if (i < OFF_B2)  { p = a2;  off = i - OFF_W2; }
  else if (i < OFF_G)   { p = a3;  off = i - OFF_B2; }
  else if (i < OFF_BT)  { p = a4;  off = i - OFF_G; }
  else if (i < OFF_FXW) { p = a5;  off = i - OFF_BT; }
  else if (i < OFF_FXB) { p = a6;  off = i - OFF_FXW; }
  else if (i < OFF_F1W) { p = a7;  off = i - OFF_FXB; }
  else if (i < OFF_F1B) { p = a8;  off = i - OFF_F1W; }
  else if (i < OFF_F2W) { p = a9;  off = i - OFF_F1B; }
  else if (i < OFF_F2B) { p = a10; off = i - OFF_F2W; }
  else if (i < OFF_OW)  { p = a11; off = i - OFF_F2B; }
  else if (i < OFF_OB)  { p = a12; off = i - OFF_OW; }
  else                  { p = a13; off = i - OFF_OB; }
  wsW[i] = isbf ? bf2f(((const unsigned short*)p)[off]) : ((const float*)p)[off];
}

// ---------------------------------------------------------------------------
// per-branch: pad/copy input x (31 -> 32 feats) to f16 rows; zero statsR+cnt
__global__ __launch_bounds__(256) void k_init(
    const void* __restrict__ xin, const void* __restrict__ gam,
    unsigned short* __restrict__ xo, float* __restrict__ statsR,
    int* __restrict__ bucketCnt)
{
  const int tid = threadIdx.x;
  const bool isbf = (*(const unsigned*)gam) == 0x3F803F80u;
  const int i = blockIdx.x * 256 + tid;
  if (blockIdx.x < 80) statsR[blockIdx.x * 256 + tid] = 0.f;  // 64*5*64 floats
  if (blockIdx.x == 0) {
    for (int s = tid; s < 512; s += 256) bucketCnt[s] = 0;
  }
  if (i >= N_NODES) return;
  H32 row;
  if (isbf) {
    const unsigned short* xs = (const unsigned short*)xin;
    #pragma unroll
    for (int f = 0; f < 31; ++f) row.h[f] = (_Float16)bf2f(xs[(size_t)i * 31 + f]);
  } else {
    const float* xs = (const float*)xin;
    #pragma unroll
    for (int f = 0; f < 31; ++f) row.h[f] = (_Float16)xs[(size_t)i * 31 + f];
  }
  row.h[31] = (_Float16)0.f;
  uint4* xw = (uint4*)(xo + (size_t)i * 32);
  #pragma unroll
  for (int q = 0; q < 4; ++q) xw[q] = row.v[q];
}

// ---------------------------------------------------------------------------
__global__ __launch_bounds__(256) void k_bhist(
    const int* __restrict__ ei, int* __restrict__ bucketCnt)
{
  __shared__ int lh[512];
  const int tid = threadIdx.x;
  for (int i = tid; i < 512; i += 256) lh[i] = 0;
  __syncthreads();
  const int e0 = blockIdx.x * EPB;
  const int e1 = min(e0 + EPB, N_EDGES);
  for (int e = e0 + tid; e < e1; e += 256)
    atomicAdd(&lh[ei[N_EDGES + e] >> 10], 1);
  __syncthreads();
  for (int i = tid; i < 512; i += 256)
    if (lh[i]) atomicAdd(&bucketCnt[i], lh[i]);
}

__global__ __launch_bounds__(512) void k_bscan(
    const int* __restrict__ bucketCnt, int* __restrict__ bucketBase,
    int* __restrict__ cursor)
{
  __shared__ int sh[512];
  const int tid = threadIdx.x;
  const int v = bucketCnt[tid];
  sh[tid] = v;
  __syncthreads();
  for (int off = 1; off < 512; off <<= 1) {
    int t = (tid >= off) ? sh[tid - off] : 0;
    __syncthreads();
    sh[tid] += t;
    __syncthreads();
  }
  const int incl = sh[tid];
  bucketBase[tid + 1] = incl;
  cursor[tid] = incl - v;
  if (tid == 0) bucketBase[0] = 0;
}

__global__ __launch_bounds__(256) void k_bscatter(
    const int* __restrict__ ei, int* __restrict__ cursor,
    unsigned* __restrict__ pairbuf)
{
  __shared__ int lh[512];
  __shared__ int cb[512];
  __shared__ int lcur[512];
  const int tid = threadIdx.x;
  for (int i = tid; i < 512; i += 256) { lh[i] = 0; lcur[i] = 0; }
  __syncthreads();
  const int e0 = blockIdx.x * EPB;
  const int e1 = min(e0 + EPB, N_EDGES);
  for (int e = e0 + tid; e < e1; e += 256)
    atomicAdd(&lh[ei[N_EDGES + e] >> 10], 1);
  __syncthreads();
  for (int i = tid; i < 512; i += 256)
    cb[i] = lh[i] ? atomicAdd(&cursor[i], lh[i]) : 0;
  __syncthreads();
  for (int e = e0 + tid; e < e1; e += 256) {
    const int s = ei[e];
    const int d = ei[N_EDGES + e];
    const int b = d >> 10;
    const int lp = atomicAdd(&lcur[b], 1);
    pairbuf[cb[b] + lp] = ((unsigned)s << 10) | (unsigned)(d & 1023);
  }
}

__global__ __launch_bounds__(256) void k_bbuild(
    const unsigned* __restrict__ pairbuf, const int* __restrict__ bucketBase,
    int* __restrict__ rowp, int* __restrict__ csr)
{
  __shared__ int hist[1024];
  __shared__ int start[1024];
  __shared__ int sh[256];
  const int tid = threadIdx.x;
  const int b = blockIdx.x;
  const int base = bucketBase[b];
  const int cnt  = bucketBase[b + 1] - base;
  const int node0 = b << 10;
  const int nodesHere = min(1024, N_NODES - node0);
  #pragma unroll
  for (int i = tid; i < 1024; i += 256) hist[i] = 0;
  __syncthreads();
  for (int p = tid; p < cnt; p += 256)
    atomicAdd(&hist[pairbuf[base + p] & 1023u], 1);
  __syncthreads();
  const int i4 = tid * 4;
  const int s0 = hist[i4], s1 = hist[i4 + 1], s2 = hist[i4 + 2], s3 = hist[i4 + 3];
  const int tsum = s0 + s1 + s2 + s3;
  sh[tid] = tsum;
  __syncthreads();
  for (int off = 1; off < 256; off <<= 1) {
    int t = (tid >= off) ? sh[tid - off] : 0;
    __syncthreads();
    sh[tid] += t;
    __syncthreads();
  }
  const int ex = sh[tid] - tsum;
  start[i4]     = ex;
  start[i4 + 1] = ex + s0;
  start[i4 + 2] = ex + s0 + s1;
  start[i4 + 3] = ex + s0 + s1 + s2;
  __syncthreads();
  #pragma unroll
  for (int i = tid; i < 1024; i += 256) {
    if (i < nodesHere) rowp[node0 + i] = base + start[i];
    hist[i] = start[i];
  }
  if (b == 0 && tid == 0) rowp[N_NODES] = N_EDGES;
  __syncthreads();
  for (int p = tid; p < cnt; p += 256) {
    const unsigned v = pairbuf[base + p];
    const int dl = (int)(v & 1023u);
    const int pos = atomicAdd(&hist[dl], 1);
    csr[base + pos] = (int)(v >> 10);
  }
}

// ---------------------------------------------------------------------------
// gather phase helper: 4-lane groups, 4 passes; indices from LDS (or global
// fallback when the block's slice overflows ECAP — wave-uniform template).
template<bool OVF>
__device__ __forceinline__ void gather_phase(
    const unsigned short* __restrict__ xin,
    const int* lidx, const int* __restrict__ gcsr, const int ebase,
    const int* sjb, const int* sdeg, _Float16* srow,
    const int node0, const int q, const int g)
{
  #pragma unroll
  for (int pass = 0; pass < 4; ++pass) {
    const int nl = pass * 64 + g;
    const int node = node0 + nl;
    const int jbl = sjb[nl] - ebase;
    const int deg = sdeg[nl];
    float acc[8];
    {
      uint4 sv = make_uint4(0u, 0u, 0u, 0u);
      if (node < N_NODES) sv = *(const uint4*)(xin + (size_t)node * 32 + 8 * q);
      H8 u; u.v = sv;
      #pragma unroll
      for (int m = 0; m < 8; ++m) acc[m] = (float)u.h[m];
    }
    for (int base = 0; base < deg; base += 8) {
      const int cnt = min(deg - base, 8);
      uint4 v[8];
      #pragma unroll
      for (int k = 0; k < 8; ++k) {
        v[k] = make_uint4(0u, 0u, 0u, 0u);
        if (k < cnt) {
          const int s = OVF ? gcsr[ebase + jbl + base + k] : lidx[jbl + base + k];
          v[k] = *(const uint4*)(xin + (size_t)s * 32 + 8 * q);
        }
      }
      #pragma unroll
      for (int k = 0; k < 8; ++k) {
        H8 u; u.v = v[k];
        #pragma unroll
        for (int m = 0; m < 8; ++m) acc[m] += (float)u.h[m];
      }
    }
    H8 o;
    #pragma unroll
    for (int m = 0; m < 8; ++m) o.h[m] = (_Float16)acc[m];
    *(uint4*)(&srow[nl * 40 + 8 * q]) = o.v;
  }
}

// fused [BN-affine of prev layer] + group gather + MLP + relu + BN-stats.
__global__ __launch_bounds__(256, 4) void k_mlp(
    const float* __restrict__ wsW, float* __restrict__ statsR,
    const unsigned short* __restrict__ xin, unsigned short* __restrict__ xo,
    const int* __restrict__ rowp, const int* __restrict__ csr, const int l)
{
  __shared__ __align__(16) float W1l[31][32];
  __shared__ __align__(16) float W2l[31][32];
  __shared__ __align__(16) float b1l[32];
  __shared__ __align__(16) float b2l[32];
  __shared__ float as_[32], cs_[32];
  __shared__ float tmp64[64];
  __shared__ float sums[64];
  __shared__ __align__(16) _Float16 srow[256 * 40];  // stride 40 halves (80B)
  __shared__ int sjb[256];
  __shared__ int sdeg[256];
  __shared__ int ldsIdx[ECAP];
  const int tid = threadIdx.x;
  const int node0 = blockIdx.x * 256;
  const int nodeEnd = min(node0 + 256, N_NODES);

  if (tid < 64) sums[tid] = 0.f;
  for (int idx = tid; idx < 992; idx += 256) {
    const int k = idx >> 5, j = idx & 31;
    float w1 = 0.f, w2 = 0.f;
    if (j < 31) {
      w1 = wsW[OFF_W1 + (l * 31 + k) * 31 + j];
      w2 = wsW[OFF_W2 + (l * 31 + k) * 31 + j];
    }
    W1l[k][j] = w1; W2l[k][j] = w2;
  }
  if (tid < 32) {
    b1l[tid] = (tid < 31) ? wsW[OFF_B1 + l * 31 + tid] : 0.f;
    b2l[tid] = (tid < 31) ? wsW[OFF_B2 + l * 31 + tid] : 0.f;
    if (l == 0) { as_[tid] = 1.f; cs_[tid] = 0.f; }
  }
  // bank-sum prev layer's replicated stats (64 banks)
  if (l > 0 && tid < 64) {
    float s = 0.f;
    #pragma unroll 8
    for (int b = 0; b < 64; ++b) s += statsR[(b * 5 + (l - 1)) * 64 + tid];
    tmp64[tid] = s;
  }
  // per-node row pointers (coalesced)
  {
    const int n = node0 + tid;
    if (n < N_NODES) {
      const int a = rowp[n];
      sjb[tid] = a; sdeg[tid] = rowp[n + 1] - a;
    } else {
      sjb[tid] = 0; sdeg[tid] = 0;
    }
  }
  // stage the block's contiguous csr slice into LDS (one coalesced sweep)
  const int ebase = rowp[node0];
  const int ecnt  = rowp[nodeEnd] - ebase;
  const bool ovf  = ecnt > ECAP;
  if (!ovf)
    for (int e = tid; e < ecnt; e += 256) ldsIdx[e] = csr[ebase + e];
  __syncthreads();
  if (l > 0 && tid < 32) {
    const float invN = 1.f / (float)N_NODES;
    const float m = tmp64[tid] * invN;
    const float v = fmaxf(tmp64[tid + 32] * invN - m * m, 0.f);
    const float rstd = rsqrtf(v + 1e-5f);
    const float g  = (tid < 31) ? wsW[OFF_G + (l - 1) * 31 + tid] : 0.f;
    const float be = (tid < 31) ? wsW[OFF_BT + (l - 1) * 31 + tid] : 0.f;
    const float a = g * rstd;
    as_[tid] = a; cs_[tid] = be - m * a;
  }

  // ---- Phase 1: gather (4 lanes per node, 4 passes) ----
  const int q = tid & 3;
  const int g = tid >> 2;
  if (!ovf) gather_phase<false>(xin, ldsIdx, csr, ebase, sjb, sdeg, srow, node0, q, g);
  else      gather_phase<true >(xin, ldsIdx, csr, ebase, sjb, sdeg, srow, node0, q, g);
  __syncthreads();

  // ---- Phase 2: per-thread MLP on own node from LDS ----
  const int i = node0 + tid;
  const bool valid = i < N_NODES;
  float h[32];
  {
    const uint4* sp = (const uint4*)(&srow[tid * 40]);
    #pragma unroll
    for (int c = 0; c < 4; ++c) {
      H8 u; u.v = sp[c];
      #pragma unroll
      for (int m = 0; m < 8; ++m) h[c * 8 + m] = (float)u.h[m];
    }
  }
  // fold prev-layer BN: h = a * (y_i + sum y_j) + (1+deg) * c
  const float degp = valid ? (float)(1 + sdeg[tid]) : 0.f;
  #pragma unroll
  for (int m = 0; m < 32; ++m) h[m] = fmaf(h[m], as_[m], degp * cs_[m]);

  float tt[32];
  {
    const float4* b1v = (const float4*)b1l;
    #pragma unroll
    for (int j4 = 0; j4 < 8; ++j4) {
      float4 a = b1v[j4];
      #pragma unroll
      for (int k = 0; k < 31; ++k) {
        const float4 w = *((const float4*)W1l[k] + j4);
        a.x = fmaf(h[k], w.x, a.x);
        a.y = fmaf(h[k], w.y, a.y);
        a.z = fmaf(h[k], w.z, a.z);
        a.w = fmaf(h[k], w.w, a.w);
      }
      tt[4 * j4 + 0] = fmaxf(a.x, 0.f);
      tt[4 * j4 + 1] = fmaxf(a.y, 0.f);
      tt[4 * j4 + 2] = fmaxf(a.z, 0.f);
      tt[4 * j4 + 3] = fmaxf(a.w, 0.f);
    }
  }
  float fs[32];
  {
    const float4* b2v = (const float4*)b2l;
    #pragma unroll
    for (int j4 = 0; j4 < 8; ++j4) {
      float4 a = b2v[j4];
      #pragma unroll
      for (int k = 0; k < 31; ++k) {
        const float4 w = *((const float4*)W2l[k] + j4);
        a.x = fmaf(tt[k], w.x, a.x);
        a.y = fmaf(tt[k], w.y, a.y);
        a.z = fmaf(tt[k], w.z, a.z);
        a.w = fmaf(tt[k], w.w, a.w);
      }
      fs[4 * j4 + 0] = fmaxf(a.x, 0.f);
      fs[4 * j4 + 1] = fmaxf(a.y, 0.f);
      fs[4 * j4 + 2] = fmaxf(a.z, 0.f);
      fs[4 * j4 + 3] = fmaxf(a.w, 0.f);
    }
  }

  if (valid) {
    H32 o;
    #pragma unroll
    for (int m = 0; m < 32; ++m) o.h[m] = (_Float16)fs[m];
    uint4* xw = (uint4*)(xo + (size_t)i * 32);
    #pragma unroll
    for (int qq = 0; qq < 4; ++qq) xw[qq] = o.v[qq];
  } else {
    #pragma unroll
    for (int m = 0; m < 32; ++m) fs[m] = 0.f;
  }

  // BN-stats: fold-exchange reduction over 64 values (sum | sumsq).
  float v64[64];
  #pragma unroll
  for (int m = 0; m < 32; ++m) { v64[m] = fs[m]; v64[32 + m] = fs[m] * fs[m]; }
  const int lane = tid & 63;
  #pragma unroll
  for (int s = 0; s < 6; ++s) {
    const int half = 32 >> s;
    const bool up = (lane >> s) & 1;
    #pragma unroll
    for (int m = 0; m < half; ++m) {
      const float mine = up ? v64[m] : v64[m + half];
      const float rcv = __shfl_xor(mine, 1 << s);
      v64[m] = (up ? v64[m + half] : v64[m]) + rcv;
    }
  }
  const int f = ((lane & 1) << 5) | ((lane & 2) << 3) | ((lane & 4) << 1) |
                ((lane >> 1) & 4) | ((lane >> 3) & 2) | ((lane >> 5) & 1);
  atomicAdd(&sums[f], v64[0]);
  __syncthreads();
  if (tid < 64)
    atomicAdd(&statsR[((blockIdx.x & 63) * 5 + l) * 64 + tid], sums[tid]);
}

// ---------------------------------------------------------------------------
// per-branch: pool pre-BN f16 y over sorted batch, apply layer-4 BN affine,
// then fc1xd + relu -> h [G,256]
__global__ __launch_bounds__(256) void k_pool(
    const float* __restrict__ wsW, const float* __restrict__ statsR,
    const unsigned short* __restrict__ xc, const int* __restrict__ batch,
    float* __restrict__ hout, float* __restrict__ hc2f, const int zero_hc)
{
  const int g = blockIdx.x;
  const int tid = threadIdx.x;
  __shared__ float a4[32], c4[32], t64[64];
  if (tid < 64) {
    float s = 0.f;
    #pragma unroll 8
    for (int b = 0; b < 64; ++b) s += statsR[(b * 5 + 4) * 64 + tid];
    t64[tid] = s;
  }
  int lo = 0, hi = N_NODES;
  while (lo < hi) { const int mid = (lo + hi) >> 1; if (batch[mid] < g) lo = mid + 1; else hi = mid; }
  const int start = lo;
  int lo2 = lo, hi2 = N_NODES;
  while (lo2 < hi2) { const int mid = (lo2 + hi2) >> 1; if (batch[mid] < g + 1) lo2 = mid + 1; else hi2 = mid; }
  const int end = lo2;
  __syncthreads();
  if (tid < 32) {
    const float invN = 1.f / (float)N_NODES;
    const float m = t64[tid] * invN;
    const float v = fmaxf(t64[tid + 32] * invN - m * m, 0.f);
    const float rstd = rsqrtf(v + 1e-5f);
    const float gg = (tid < 31) ? wsW[OFF_G + 4 * 31 + tid] : 0.f;
    const float be = (tid < 31) ? wsW[OFF_BT + 4 * 31 + tid] : 0.f;
    const float a = gg * rstd;
    a4[tid] = a; c4[tid] = be - m * a;
  }

  __shared__ float part[8][33];
  __shared__ float pooled[32];
  const int ff_ = tid & 31, n8 = tid >> 5;
  float p = 0.f;
  const _Float16* xh = (const _Float16*)xc;
  for (int n = start + n8; n < end; n += 8) p += (float)xh[(size_t)n * 32 + ff_];
  part[n8][ff_] = p;
  __syncthreads();
  if (tid < 32) {
    float s = 0.f;
    #pragma unroll
    for (int m = 0; m < 8; ++m) s += part[m][tid];
    pooled[tid] = fmaf(s, a4[tid], (float)(end - start) * c4[tid]);
  }
  __syncthreads();

  float acc = wsW[OFF_FXB + tid];
  for (int ff = 0; ff < 31; ++ff)
    acc = fmaf(pooled[ff], wsW[OFF_FXW + ff * 256 + tid], acc);
  hout[(size_t)g * 256 + tid] = fmaxf(acc, 0.f);
  if (zero_hc) hc2f[(size_t)g * 256 + tid] = 0.f;
}

// ---------------------------------------------------------------------------
// 64x64-tile f32 GEMM. ADD2: A := A + A2 elementwise on load.
// ATOMIC=false: C = relu(acc + bias); ATOMIC=true: atomicAdd into C.
template <bool ADD2, bool ATOMIC>
__global__ __launch_bounds__(256) void k_gemm(
    const float* __restrict__ A, const float* __restrict__ A2,
    const float* __restrict__ B, const float* __restrict__ bias,
    float* __restrict__ C, const int M, const int N, const int K)
{
  __shared__ __align__(16) float AT[64 * 66];
  __shared__ __align__(16) float BT[64 * 66];
  const int tid = threadIdx.x;
  const int row0 = blockIdx.x * 64;
  const int col0 = blockIdx.y * 64;
  const int ktiles = (K / 64) / gridDim.z;
  const int ktbase = blockIdx.z * ktiles;
  float acc[16];
  #pragma unroll
  for (int m = 0; m < 16; ++m) acc[m] = 0.f;
  const int ar = tid >> 2, akq = tid & 3;
  const int bk = tid >> 4, bc = (tid & 15) * 4;
  const int r0 = (tid >> 4) * 4, c0l = (tid & 15) * 4;

  for (int kt = 0; kt < ktiles; ++kt) {
    const int k0 = (ktbase + kt) * 64;
    #pragma unroll
    for (int m = 0; m < 4; ++m) {
      const int k = akq * 16 + m * 4;
      float4 v = *(const float4*)(A + (size_t)(row0 + ar) * K + (k0 + k));
      if constexpr (ADD2) {
        const float4 q = *(const float4*)(A2 + (size_t)(row0 + ar) * K + (k0 + k));
        v.x += q.x; v.y += q.y; v.z += q.z; v.w += q.w;
      }
      AT[(k + 0) * 66 + ar] = v.x; AT[(k + 1) * 66 + ar] = v.y;
      AT[(k + 2) * 66 + ar] = v.z; AT[(k + 3) * 66 + ar] = v.w;
    }
    #pragma unroll
    for (int m = 0; m < 4; ++m) {
      const int k = bk + m * 16;
      const float4 v = *(const float4*)(B + (size_t)(k0 + k) * N + col0 + bc);
      BT[k * 66 + bc + 0] = v.x; BT[k * 66 + bc + 1] = v.y;
      BT[k * 66 + bc + 2] = v.z; BT[k * 66 + bc + 3] = v.w;
    }
    __syncthreads();
    #pragma unroll 8
    for (int k = 0; k < 64; ++k) {
      const float* ap = &AT[k * 66 + r0];
      const float* bp = &BT[k * 66 + c0l];
      const float a0 = ap[0], a1 = ap[1], a2 = ap[2], a3 = ap[3];
      const float b0 = bp[0], b1 = bp[1], b2 = bp[2], b3 = bp[3];
      acc[0]  = fmaf(a0, b0, acc[0]);  acc[1]  = fmaf(a0, b1, acc[1]);
      acc[2]  = fmaf(a0, b2, acc[2]);  acc[3]  = fmaf(a0, b3, acc[3]);
      acc[4]  = fmaf(a1, b0, acc[4]);  acc[5]  = fmaf(a1, b1, acc[5]);
      acc[6]  = fmaf(a1, b2, acc[6]);  acc[7]  = fmaf(a1, b3, acc[7]);
      acc[8]  = fmaf(a2, b0, acc[8]);  acc[9]  = fmaf(a2, b1, acc[9]);
      acc[10] = fmaf(a2, b2, acc[10]); acc[11] = fmaf(a2, b3, acc[11]);
      acc[12] = fmaf(a3, b0, acc[12]); acc[13] = fmaf(a3, b1, acc[13]);
      acc[14] = fmaf(a3, b2, acc[14]); acc[15] = fmaf(a3, b3, acc[15]);
    }
    __syncthreads();
  }

  if constexpr (ATOMIC) {
    #pragma unroll
    for (int ii = 0; ii < 4; ++ii)
      #pragma unroll
      for (int jj = 0; jj < 4; ++jj)
        atomicAdd(&C[(size_t)(row0 + r0 + ii) * N + col0 + c0l + jj], acc[4 * ii + jj]);
  } else {
    #pragma unroll
    for (int ii = 0; ii < 4; ++ii) {
      float4 st;
      st.x = fmaxf(acc[4 * ii + 0] + bias[col0 + c0l + 0], 0.f);
      st.y = fmaxf(acc[4 * ii + 1] + bias[col0 + c0l + 1], 0.f);
      st.z = fmaxf(acc[4 * ii + 2] + bias[col0 + c0l + 2], 0.f);
      st.w = fmaxf(acc[4 * ii + 3] + bias[col0 + c0l + 3], 0.f);
      *(float4*)(C + (size_t)(row0 + r0 + ii) * N + col0 + c0l) = st;
    }
  }
}

// ---------------------------------------------------------------------------
__global__ __launch_bounds__(256) void k_out(
    const float* __restrict__ wsW, const float* __restrict__ hc2f,
    void* __restrict__ dout, const void* __restrict__ gam)
{
  const int tid = threadIdx.x;
  const int g = blockIdx.x * 4 + (tid >> 6);
  const int lane = tid & 63;
  float p0 = 0.f, p1 = 0.f;
  #pragma unroll
  for (int m = 0; m < 4; ++m) {
    const int k = lane + m * 64;
    const float v = fmaxf(hc2f[(size_t)g * 256 + k] + wsW[OFF_F2B + k], 0.f);
    p0 = fmaf(v, wsW[OFF_OW + 2 * k], p0);
    p1 = fmaf(v, wsW[OFF_OW + 2 * k + 1], p1);
  }
  #pragma unroll
  for (int st = 0; st < 6; ++st) {
    const int msk = 1 << st;
    p0 += __shfl_xor(p0, msk);
    p1 += __shfl_xor(p1, msk);
  }
  if (lane == 0) {
    const float o0 = p0 + wsW[OFF_OB];
    const float o1 = p1 + wsW[OFF_OB + 1];
    const bool isbf = (*(const unsigned*)gam) == 0x3F803F80u;
    if (isbf) {
      unsigned short* o = (unsigned short*)dout;
      o[2 * g] = f2bf(o0); o[2 * g + 1] = f2bf(o1);
    } else {
      float* o = (float*)dout;
      o[2 * g] = o0; o[2 * g + 1] = o1;
    }
  }
}

// ===========================================================================
extern "C" void kernel_launch(void* const* d_in, const int* in_sizes, int n_in,
                              void* d_out, int out_size, void* d_ws, size_t ws_size,
                              hipStream_t stream)
{
  (void)in_sizes; (void)n_in; (void)out_size; (void)ws_size;
  char* ws = (char*)d_ws;
  unsigned short* act0 = (unsigned short*)(ws + 0ull);          // 32,000,000
  unsigned short* act1 = (unsigned short*)(ws + 32000000ull);   // 32,000,000
  int* csr         = (int*)(ws + 64000000ull);      //  8,000,000
  int* rowp        = (int*)(ws + 72000000ull);      //  2,000,016
  int* bucketBase  = (int*)(ws + 74000016ull);      //      2,064
  int* cursor      = (int*)(ws + 74002080ull);      //      2,048
  int* bucketCnt   = (int*)(ws + 74004128ull);      //      2,048
  float* statsR    = (float*)(ws + 74006176ull);    //     81,920 (64 banks x 5 x 64)
  float* wsW       = (float*)(ws + 74088096ull);    //  2,178,016
  float* ha        = (float*)(ws + 76266112ull);    //  4,194,304
  float* hb        = (float*)(ws + 80460416ull);    //  4,194,304
  float* xcb       = (float*)(ws + 84654720ull);    // 16,777,216 (aliases pairbuf)
  float* hc2f      = (float*)(ws + 101431936ull);   //  4,194,304
  unsigned* pairbuf = (unsigned*)xcb;               //  8,000,000 (pre-GEMM only)
  // total ~105.6 MB

  const void* gam = d_in[10];

  k_convert<<<dim3(2127), 256, 0, stream>>>(
      d_in[6], d_in[7], d_in[8], d_in[9], d_in[10], d_in[11], d_in[12],
      d_in[13], d_in[14], d_in[15], d_in[16], d_in[17], d_in[18], d_in[19], wsW);

  for (int br = 0; br < 2; ++br) {
    const void* x_in = br ? d_in[3] : d_in[0];
    const int* ei    = (const int*)(br ? d_in[4] : d_in[1]);
    const int* batch = (const int*)(br ? d_in[5] : d_in[2]);
    float* hout      = br ? hb : ha;

    k_init<<<dim3(1954), 256, 0, stream>>>(x_in, gam, act0, statsR, bucketCnt);
    k_bhist<<<dim3(512), 256, 0, stream>>>(ei, bucketCnt);
    k_bscan<<<dim3(1), 512, 0, stream>>>(bucketCnt, bucketBase, cursor);
    k_bscatter<<<dim3(512), 256, 0, stream>>>(ei, cursor, pairbuf);
    k_bbuild<<<dim3(NB), 256, 0, stream>>>(pairbuf, bucketBase, rowp, csr);

    unsigned short* bufs[2] = {act0, act1};
    for (int l = 0; l < 5; ++l) {
      unsigned short* xin = bufs[l & 1];
      unsigned short* xo  = bufs[(l + 1) & 1];
      k_mlp<<<dim3(1954), 256, 0, stream>>>(wsW, statsR, xin, xo, rowp, csr, l);
    }
    // after 5 layers, pre-BN activations live in act1 (layer-4 BN in pool)
    k_pool<<<dim3(4096), 256, 0, stream>>>(wsW, statsR, act1, batch, hout, hc2f, br == 0 ? 1 : 0);
  }

  k_gemm<true, false><<<dim3(64, 16, 1), 256, 0, stream>>>(
      ha, hb, wsW + OFF_F1W, wsW + OFF_F1B, xcb, 4096, 1024, 256);
  k_gemm<false, true><<<dim3(64, 4, 4), 256, 0, stream>>>(
      xcb, (const float*)nullptr, wsW + OFF_F2W, (const float*)nullptr,
      hc2f, 4096, 256, 1024);
  k_out<<<dim3(1024), 256, 0, stream>>>(wsW, hc2f, d_out, gam);
}